// Round 1
// baseline (794.937 us; speedup 1.0000x reference)
//
#include <hip/hip_runtime.h>
#include <stdint.h>
#include <string.h>
#include <math.h>

// ---------------------------------------------------------------------------
// FlashThermodynamicAttention: exact replication of the JAX reference.
// Output depends ONLY on v: per-head 8x8 Ising grids, 16 Gibbs steps
// (2 diffusion betas x 8 sweeps), checkerboard half-sweeps, threefry RNG.
//
// Variant ladder (flip on failure in later rounds):
//   RNG_MODE: 0 = partitionable threefry (per-element counter (0,m), bits=y0^y1)
//             1 = partitionable, bits = y0 only
//             2 = legacy (non-partitionable): paired counters (m, m+half)
//   EXP_MODE: 0 = XLA:CPU Cephes expf, non-fused mul/add
//             1 = same but fused (fmaf)
//             2 = correctly-rounded (double) exp
//   BETA_MODE:0 = glibc/double-rounded log+exp (jit const-folding via HloEvaluator)
//             1 = Cephes log+exp chain (eager/unfolded)
// ---------------------------------------------------------------------------
#define RNG_MODE 0
#define EXP_MODE 0
#define BETA_MODE 0

struct FtaParams {
  uint32_t hk[32][2];   // key for each of 16 steps x 2 half-sweeps
  uint32_t kcut[2][9];  // integer cutoff: update to +1 iff (bits>>9) < kcut[beta][h+4]
};

// Threefry-2x32, 20 rounds (matches jax._src.prng.threefry2x32 exactly).
__host__ __device__ static inline void tf2x32(uint32_t k0, uint32_t k1,
                                              uint32_t c0, uint32_t c1,
                                              uint32_t& o0, uint32_t& o1) {
  uint32_t ks2 = k0 ^ k1 ^ 0x1BD11BDAu;
  uint32_t x0 = c0 + k0, x1 = c1 + k1;
#define TFR(r) { x0 += x1; x1 = (x1 << (r)) | (x1 >> (32 - (r))); x1 ^= x0; }
  TFR(13) TFR(15) TFR(26) TFR(6)
  x0 += k1;  x1 += ks2 + 1u;
  TFR(17) TFR(29) TFR(16) TFR(24)
  x0 += ks2; x1 += k0 + 2u;
  TFR(13) TFR(15) TFR(26) TFR(6)
  x0 += k0;  x1 += k1 + 3u;
  TFR(17) TFR(29) TFR(16) TFR(24)
  x0 += k1;  x1 += ks2 + 4u;
  TFR(13) TFR(15) TFR(26) TFR(6)
  x0 += ks2; x1 += k0 + 5u;
#undef TFR
  o0 = x0; o1 = x1;
}

// ---------------------------------------------------------------------------
// Host-side math emulation of the reference's float32 numerics.
// ---------------------------------------------------------------------------

// XLA:CPU vectorized expf (llvm_ir_runtime / polynomial_approximations):
// classic Cephes/Eigen pexp<float>. EXP_MODE selects mul+add vs fmaf.
static float xla_expf(float xin) {
#if EXP_MODE == 2
  return (float)exp((double)xin);
#else
  const float exp_hi = 88.3762626647950f;
  const float exp_lo = -88.3762626647949f;
  const float LOG2EF = 1.44269504088896341f;
  const float C1 = 0.693359375f;
  const float C2 = -2.12194440e-4f;
  const float Pc0 = 1.9875691500E-4f;
  const float Pc1 = 1.3981999507E-3f;
  const float Pc2 = 8.3334519073E-3f;
  const float Pc3 = 4.1665795894E-2f;
  const float Pc4 = 1.6666665459E-1f;
  const float Pc5 = 5.0000001201E-1f;
#if EXP_MODE == 1
#define MA(a, b, c) fmaf((a), (b), (c))
#else
#define MA(a, b, c) ((a) * (b) + (c))
#endif
  float x = xin;
  if (x > exp_hi) x = exp_hi;
  if (x < exp_lo) x = exp_lo;
  float fx = floorf(MA(x, LOG2EF, 0.5f));
  float tmp = C1 * fx;
  float z = C2 * fx;
  x = x - tmp;
  x = x - z;
  z = x * x;
  float y = MA(x, Pc0, Pc1);
  y = MA(y, x, Pc2);
  y = MA(y, x, Pc3);
  y = MA(y, x, Pc4);
  y = MA(y, x, Pc5);
  y = MA(y, z, x);
  y = y + 1.0f;
  int nn = (int)fx;
  uint32_t eb = (uint32_t)(nn + 127) << 23;
  float p2n;
  memcpy(&p2n, &eb, 4);
  float r = y * p2n;
  return r > xin ? r : xin;
#undef MA
#endif
}

#if BETA_MODE == 1
// XLA:CPU vectorized logf (Cephes plog), non-fused.
static float xla_logf(float xx) {
  const float SQRTHF = 0.707106781186547524f;
  const float L0 = 7.0376836292E-2f,  L1 = -1.1514610310E-1f, L2 = 1.1676998740E-1f,
              L3 = -1.2420140846E-1f, L4 = 1.4249322787E-1f,  L5 = -1.6668057665E-1f,
              L6 = 2.0000714765E-1f,  L7 = -2.4999993993E-1f, L8 = 3.3333331174E-1f;
  const float Q1 = -2.12194440e-4f, Q2 = 0.693359375f;
  int e;
  float m = frexpf(xx, &e);
  float fe = (float)e;
  if (m < SQRTHF) { fe -= 1.0f; m = m + m - 1.0f; } else { m = m - 1.0f; }
  float z = m * m;
  float y = L0;
  y = y * m + L1; y = y * m + L2; y = y * m + L3; y = y * m + L4;
  y = y * m + L5; y = y * m + L6; y = y * m + L7; y = y * m + L8;
  y = y * m;
  y = y * z;
  y = y + fe * Q1;
  y = y - 0.5f * z;
  float r = m + y;
  r = r + fe * Q2;
  return r;
}
#endif

// ---------------------------------------------------------------------------
// Device kernel: one thread per (b, h, n) 8x8 grid; spins as 64-bit bitboard.
// ---------------------------------------------------------------------------
__global__ __launch_bounds__(256) void fta_kernel(const float* __restrict__ v,
                                                  float* __restrict__ out,
                                                  FtaParams P) {
  __shared__ uint32_t sKC[18];
  if (threadIdx.x < 9) sKC[threadIdx.x] = P.kcut[0][threadIdx.x];
  else if (threadIdx.x < 18) sKC[threadIdx.x] = P.kcut[1][threadIdx.x - 9];
  __syncthreads();

  uint32_t tid = blockIdx.x * 256u + threadIdx.x;   // tid = ((b*16+h)*4096+n)
  uint32_t b = tid >> 16;
  uint32_t h = (tid >> 12) & 15u;
  uint32_t n = tid & 4095u;

  // v / out layout: (B, N, D) with D = h*64 + (i*8+j); row is 64 contiguous floats.
  size_t voff = ((size_t)(b * 4096u + n)) * 1024u + (size_t)h * 64u;

  uint64_t bd = 0;  // bit k = i*8+j; 1 <-> spin +1
#pragma unroll
  for (int k = 0; k < 64; k += 4) {
    float4 a = *reinterpret_cast<const float4*>(v + voff + k);
    bd |= ((uint64_t)(a.x > 0.0f)) << (k + 0);
    bd |= ((uint64_t)(a.y > 0.0f)) << (k + 1);
    bd |= ((uint64_t)(a.z > 0.0f)) << (k + 2);
    bd |= ((uint64_t)(a.w > 0.0f)) << (k + 3);
  }

  uint32_t mbase = tid * 64u;  // flat index of site (b,h,n,0,0) in (B,H,N,8,8)
#if RNG_MODE == 2
  const uint32_t HALF = 8388608u;
  bool hiWord = (b >= 2);
  uint32_t cbase = hiWord ? (mbase - HALF) : mbase;
#endif

  for (int t = 0; t < 16; ++t) {
    uint32_t koff = (uint32_t)((t >> 3) * 9);
    for (int hf = 0; hf < 2; ++hf) {
      uint32_t K0 = P.hk[2 * t + hf][0];
      uint32_t K1 = P.hk[2 * t + hf][1];
      for (int i = 0; i < 8; ++i) {
        int j0 = (i + 1 + hf) & 1;  // hf=0: update (i+j) odd; hf=1: (i+j) even
#pragma unroll
        for (int jj = 0; jj < 4; ++jj) {
          int j = 2 * jj + j0;
          int k = i * 8 + j;
          uint32_t r0, r1, bits;
#if RNG_MODE == 2
          tf2x32(K0, K1, cbase + (uint32_t)k, cbase + (uint32_t)k + HALF, r0, r1);
          bits = hiWord ? r1 : r0;
#else
          tf2x32(K0, K1, 0u, mbase + (uint32_t)k, r0, r1);
#if RNG_MODE == 0
          bits = r0 ^ r1;
#else
          bits = r0;
#endif
#endif
          // neighbor field (open boundary): h = 2*cnt - navail, idx = h+4
          int navail = 4 - (i == 0) - (i == 7) - (j == 0) - (j == 7);
          uint32_t cnt = 0;
          if (i < 7) cnt += (uint32_t)(bd >> (k + 8)) & 1u;
          if (i > 0) cnt += (uint32_t)(bd >> (k - 8)) & 1u;
          if (j < 7) cnt += (uint32_t)(bd >> (k + 1)) & 1u;
          if (j > 0) cnt += (uint32_t)(bd >> (k - 1)) & 1u;
          uint32_t idx = 2u * cnt + (uint32_t)(4 - navail);
          uint64_t bit = ((bits >> 9) < sKC[koff + idx]) ? 1ull : 0ull;
          bd = (bd & ~(1ull << k)) | (bit << k);
        }
      }
    }
  }

#pragma unroll
  for (int k = 0; k < 64; k += 4) {
    float4 o;
    o.x = ((bd >> (k + 0)) & 1ull) ? 1.0f : -1.0f;
    o.y = ((bd >> (k + 1)) & 1ull) ? 1.0f : -1.0f;
    o.z = ((bd >> (k + 2)) & 1ull) ? 1.0f : -1.0f;
    o.w = ((bd >> (k + 3)) & 1ull) ? 1.0f : -1.0f;
    *reinterpret_cast<float4*>(out + voff + k) = o;
  }
}

// ---------------------------------------------------------------------------
extern "C" void kernel_launch(void* const* d_in, const int* in_sizes, int n_in,
                              void* d_out, int out_size, void* d_ws, size_t ws_size,
                              hipStream_t stream) {
  (void)in_sizes; (void)n_in; (void)d_ws; (void)ws_size; (void)out_size;
  const float* v = (const float*)d_in[2];  // inputs: q, k, v — only v used
  float* out = (float*)d_out;

  FtaParams P;

  // ---- key derivation (host, exact integer math) ----
  const uint32_t rk0 = 0u, rk1 = 1234u;  // jax.random.key(1234) -> (0, 1234)
  uint32_t kt[16][2];
#if RNG_MODE == 2
  // legacy split: counts = iota(32); pairs (i, 16+i); keys[t] = (flat[2t], flat[2t+1])
  uint32_t A[16], Bv[16], flat[32];
  for (uint32_t i = 0; i < 16; ++i) tf2x32(rk0, rk1, i, 16u + i, A[i], Bv[i]);
  for (int i = 0; i < 16; ++i) { flat[i] = A[i]; flat[16 + i] = Bv[i]; }
  for (int t = 0; t < 16; ++t) { kt[t][0] = flat[2 * t]; kt[t][1] = flat[2 * t + 1]; }
  for (int t = 0; t < 16; ++t) {
    uint32_t e0a, e0b, e1a, e1b;
    tf2x32(kt[t][0], kt[t][1], 0u, 2u, e0a, e0b);  // pair (0,2)
    tf2x32(kt[t][0], kt[t][1], 1u, 3u, e1a, e1b);  // pair (1,3)
    P.hk[2 * t + 0][0] = e0a; P.hk[2 * t + 0][1] = e1a;  // k0 = (y0(p0), y0(p1))
    P.hk[2 * t + 1][0] = e0b; P.hk[2 * t + 1][1] = e1b;  // k1 = (y1(p0), y1(p1))
  }
#else
  // partitionable fold-like split: child j = cipher(key, (0, j)) -> (y0, y1)
  for (uint32_t t = 0; t < 16; ++t) tf2x32(rk0, rk1, 0u, t, kt[t][0], kt[t][1]);
  for (int t = 0; t < 16; ++t) {
    uint32_t a0, a1, b0, b1;
    tf2x32(kt[t][0], kt[t][1], 0u, 0u, a0, a1);  // k0 (first half-sweep)
    tf2x32(kt[t][0], kt[t][1], 0u, 1u, b0, b1);  // k1 (second half-sweep)
    P.hk[2 * t + 0][0] = a0; P.hk[2 * t + 0][1] = a1;
    P.hk[2 * t + 1][0] = b0; P.hk[2 * t + 1][1] = b1;
  }
#endif

  // ---- betas ----
  float bet[2];
#if BETA_MODE == 0
  // jit const-folding path: HloEvaluator -> glibc expf/logf ~= double-rounded
  bet[0] = (float)exp((double)(float)log((double)0.8f));
  bet[1] = (float)exp((double)(float)log((double)1.2f));
#else
  bet[0] = xla_expf(xla_logf(0.8f));
  bet[1] = xla_expf(xla_logf(1.2f));
#endif

  // ---- sigmoid cutoffs: u < p  <=>  (bits>>9) < ceil(p * 2^23) ----
  for (int s = 0; s < 2; ++s) {
    float x2b = 2.0f * bet[s];
    for (int hh = -4; hh <= 4; ++hh) {
      float xh = x2b * (float)hh;       // fl(2*beta*h), as in JAX
      float e = xla_expf(-xh);          // exp(-x)
      float p = 1.0f / (1.0f + e);      // LogisticExpander form
      double pd = (double)p * 8388608.0;  // exact in double
      P.kcut[s][hh + 4] = (uint32_t)ceil(pd);
    }
  }

  fta_kernel<<<dim3(1024), dim3(256), 0, stream>>>(v, out, P);
}

// Round 2
// 536.353 us; speedup vs baseline: 1.4821x; 1.4821x over previous
//
#include <hip/hip_runtime.h>
#include <stdint.h>
#include <string.h>
#include <math.h>

// ---------------------------------------------------------------------------
// FlashThermodynamicAttention — exact replication of the JAX reference.
// Verified bit-exact in R0 (absmax = 0): partitionable threefry
// (counter (0, m), bits = y0 ^ y1), XLA:CPU Cephes expf (non-fused),
// betas via double-rounded log/exp (jit const-folding).
//
// R1: same math, optimized schedule:
//   - bit-sliced SWAR neighbor counts (planes c0,c1,c2 for all 64 sites)
//   - no LDS: threshold select via cndmask tree on wave-uniform K<<9 values
//   - independent per-site accumulate (breaks the bd RMW serial chain)
// ---------------------------------------------------------------------------

struct FtaParams {
  uint32_t hk[32][2];   // threefry key for each of 16 steps x 2 half-sweeps
  uint32_t K9[2][9];    // (cutoff << 9): update to +1 iff bits < K9[beta][h+4]
};

// Threefry-2x32, 20 rounds (matches jax._src.prng.threefry2x32 exactly).
__host__ __device__ static inline void tf2x32(uint32_t k0, uint32_t k1,
                                              uint32_t c0, uint32_t c1,
                                              uint32_t& o0, uint32_t& o1) {
  uint32_t ks2 = k0 ^ k1 ^ 0x1BD11BDAu;
  uint32_t x0 = c0 + k0, x1 = c1 + k1;
#define TFR(r) { x0 += x1; x1 = (x1 << (r)) | (x1 >> (32 - (r))); x1 ^= x0; }
  TFR(13) TFR(15) TFR(26) TFR(6)
  x0 += k1;  x1 += ks2 + 1u;
  TFR(17) TFR(29) TFR(16) TFR(24)
  x0 += ks2; x1 += k0 + 2u;
  TFR(13) TFR(15) TFR(26) TFR(6)
  x0 += k0;  x1 += k1 + 3u;
  TFR(17) TFR(29) TFR(16) TFR(24)
  x0 += k1;  x1 += ks2 + 4u;
  TFR(13) TFR(15) TFR(26) TFR(6)
  x0 += ks2; x1 += k0 + 5u;
#undef TFR
  o0 = x0; o1 = x1;
}

// XLA:CPU vectorized expf (Cephes/Eigen pexp<float>), non-fused mul/add.
static float xla_expf(float xin) {
  const float exp_hi = 88.3762626647950f;
  const float exp_lo = -88.3762626647949f;
  const float LOG2EF = 1.44269504088896341f;
  const float C1 = 0.693359375f;
  const float C2 = -2.12194440e-4f;
  const float Pc0 = 1.9875691500E-4f;
  const float Pc1 = 1.3981999507E-3f;
  const float Pc2 = 8.3334519073E-3f;
  const float Pc3 = 4.1665795894E-2f;
  const float Pc4 = 1.6666665459E-1f;
  const float Pc5 = 5.0000001201E-1f;
#define MA(a, b, c) ((a) * (b) + (c))
  float x = xin;
  if (x > exp_hi) x = exp_hi;
  if (x < exp_lo) x = exp_lo;
  float fx = floorf(MA(x, LOG2EF, 0.5f));
  float tmp = C1 * fx;
  float z = C2 * fx;
  x = x - tmp;
  x = x - z;
  z = x * x;
  float y = MA(x, Pc0, Pc1);
  y = MA(y, x, Pc2);
  y = MA(y, x, Pc3);
  y = MA(y, x, Pc4);
  y = MA(y, x, Pc5);
  y = MA(y, z, x);
  y = y + 1.0f;
  int nn = (int)fx;
  uint32_t eb = (uint32_t)(nn + 127) << 23;
  float p2n;
  memcpy(&p2n, &eb, 4);
  float r = y * p2n;
  return r > xin ? r : xin;
#undef MA
}

// ---------------------------------------------------------------------------
// Device kernel: one thread per (b, h, n) 8x8 grid; spins as 64-bit bitboard.
// ---------------------------------------------------------------------------
__global__ __launch_bounds__(256) void fta_kernel(const float* __restrict__ v,
                                                  float* __restrict__ out,
                                                  FtaParams P) {
  uint32_t tid = blockIdx.x * 256u + threadIdx.x;   // tid = ((b*16+h)*4096+n)
  uint32_t b = tid >> 16;
  uint32_t h = (tid >> 12) & 15u;
  uint32_t n = tid & 4095u;

  // v / out layout: (B, N, D) with D = h*64 + (i*8+j); row is 64 contiguous floats.
  size_t voff = ((size_t)(b * 4096u + n)) * 1024u + (size_t)h * 64u;

  uint64_t bd = 0;  // bit k = i*8+j; 1 <-> spin +1
#pragma unroll
  for (int k = 0; k < 64; k += 4) {
    float4 a = *reinterpret_cast<const float4*>(v + voff + k);
    bd |= ((uint64_t)(a.x > 0.0f)) << (k + 0);
    bd |= ((uint64_t)(a.y > 0.0f)) << (k + 1);
    bd |= ((uint64_t)(a.z > 0.0f)) << (k + 2);
    bd |= ((uint64_t)(a.w > 0.0f)) << (k + 3);
  }

  uint32_t mbase = tid * 64u;  // flat index of site (b,h,n,0,0) in (B,H,N,8,8)

  // Threshold set for the current beta (switches at t == 8). Constant indices
  // only -> stays in registers.
  uint32_t K[9];
#pragma unroll
  for (int q = 0; q < 9; ++q) K[q] = P.K9[0][q];

  // Checkerboard masks: hf=0 updates (i+j) odd, hf=1 updates (i+j) even.
  const uint64_t PMASK[2] = { 0x55AA55AA55AA55AAull, 0xAA55AA55AA55AA55ull };

  for (int t = 0; t < 16; ++t) {
    if (t == 8) {
#pragma unroll
      for (int q = 0; q < 9; ++q) K[q] = P.K9[1][q];
    }
#pragma unroll
    for (int hf = 0; hf < 2; ++hf) {
      uint32_t K0 = P.hk[2 * t + hf][0];
      uint32_t K1 = P.hk[2 * t + hf][1];

      // ---- bit-sliced neighbor counts for all 64 sites ----
      uint64_t U = bd >> 8;                                   // s[i+1][j]
      uint64_t D = bd << 8;                                   // s[i-1][j]
      uint64_t L = (bd >> 1) & 0x7f7f7f7f7f7f7f7full;         // s[i][j+1]
      uint64_t R = (bd << 1) & 0xfefefefefefefefeull;         // s[i][j-1]
      uint64_t t0 = U ^ D, ca = U & D;
      uint64_t t1 = L ^ R, cb = L & R;
      uint64_t c0 = t0 ^ t1, cc = t0 & t1;
      uint64_t cx = ca ^ cb;
      uint64_t c1 = cx ^ cc;
      uint64_t c2 = (ca & cb) | (cc & cx);

      uint32_t accLo = 0u, accHi = 0u;
#pragma unroll
      for (int i = 0; i < 8; ++i) {
        const int j0 = (i + 1 + hf) & 1;
#pragma unroll
        for (int jj = 0; jj < 4; ++jj) {
          const int j = 2 * jj + j0;
          const int k = i * 8 + j;
          uint32_t r0, r1;
          tf2x32(K0, K1, 0u, mbase + (uint32_t)k, r0, r1);
          uint32_t bits = r0 ^ r1;

          uint32_t b0 = (uint32_t)(c0 >> k) & 1u;
          uint32_t b1 = (uint32_t)(c1 >> k) & 1u;
          // boundary class: e = #missing neighbors; idx = 2*cnt + e
          const int e = (int)(i == 0) + (int)(i == 7) + (int)(j == 0) + (int)(j == 7);
          uint32_t thr;
          if (e == 0) {            // interior: K[0,2,4,6,8] by cnt 0..4
            uint32_t b2 = (uint32_t)(c2 >> k) & 1u;
            uint32_t tA = b0 ? K[2] : K[0];
            uint32_t tB = b0 ? K[6] : K[4];
            uint32_t tC = b1 ? tB : tA;
            thr = b2 ? K[8] : tC;
          } else if (e == 1) {     // edge: K[1,3,5,7] by cnt 0..3
            uint32_t tA = b0 ? K[3] : K[1];
            uint32_t tB = b0 ? K[7] : K[5];
            thr = b1 ? tB : tA;
          } else {                 // corner: K[2,4,6] by cnt 0..2
            uint32_t tA = b0 ? K[4] : K[2];
            thr = b1 ? K[6] : tA;
          }

          uint32_t nb = (bits < thr) ? 1u : 0u;
          if (k < 32) accLo |= nb << k;
          else        accHi |= nb << (k - 32);
        }
      }
      uint64_t acc = ((uint64_t)accHi << 32) | (uint64_t)accLo;
      bd = (bd & ~PMASK[hf]) | acc;
    }
  }

#pragma unroll
  for (int k = 0; k < 64; k += 4) {
    float4 o;
    o.x = ((bd >> (k + 0)) & 1ull) ? 1.0f : -1.0f;
    o.y = ((bd >> (k + 1)) & 1ull) ? 1.0f : -1.0f;
    o.z = ((bd >> (k + 2)) & 1ull) ? 1.0f : -1.0f;
    o.w = ((bd >> (k + 3)) & 1ull) ? 1.0f : -1.0f;
    *reinterpret_cast<float4*>(out + voff + k) = o;
  }
}

// ---------------------------------------------------------------------------
extern "C" void kernel_launch(void* const* d_in, const int* in_sizes, int n_in,
                              void* d_out, int out_size, void* d_ws, size_t ws_size,
                              hipStream_t stream) {
  (void)in_sizes; (void)n_in; (void)d_ws; (void)ws_size; (void)out_size;
  const float* v = (const float*)d_in[2];  // inputs: q, k, v — only v used
  float* out = (float*)d_out;

  FtaParams P;

  // ---- key derivation (host, exact integer math) ----
  const uint32_t rk0 = 0u, rk1 = 1234u;  // jax.random.key(1234) -> (0, 1234)
  uint32_t kt[16][2];
  // partitionable fold-like split: child j = cipher(key, (0, j)) -> (y0, y1)
  for (uint32_t t = 0; t < 16; ++t) tf2x32(rk0, rk1, 0u, t, kt[t][0], kt[t][1]);
  for (int t = 0; t < 16; ++t) {
    uint32_t a0, a1, b0, b1;
    tf2x32(kt[t][0], kt[t][1], 0u, 0u, a0, a1);  // k0 (first half-sweep)
    tf2x32(kt[t][0], kt[t][1], 0u, 1u, b0, b1);  // k1 (second half-sweep)
    P.hk[2 * t + 0][0] = a0; P.hk[2 * t + 0][1] = a1;
    P.hk[2 * t + 1][0] = b0; P.hk[2 * t + 1][1] = b1;
  }

  // ---- betas: jit const-folding path (HloEvaluator -> double-rounded) ----
  float bet[2];
  bet[0] = (float)exp((double)(float)log((double)0.8f));
  bet[1] = (float)exp((double)(float)log((double)1.2f));

  // ---- sigmoid cutoffs: u < p  <=>  bits < (ceil(p * 2^23) << 9) ----
  for (int s = 0; s < 2; ++s) {
    float x2b = 2.0f * bet[s];
    for (int hh = -4; hh <= 4; ++hh) {
      float xh = x2b * (float)hh;       // fl(2*beta*h), as in JAX
      float e = xla_expf(-xh);          // exp(-x)
      float p = 1.0f / (1.0f + e);      // LogisticExpander form
      double pd = (double)p * 8388608.0;  // exact in double
      uint64_t kc = (uint64_t)ceil(pd);
      uint64_t k9 = kc << 9;
      P.K9[s][hh + 4] = (k9 > 0xFFFFFFFFull) ? 0xFFFFFFFFu : (uint32_t)k9;
    }
  }

  fta_kernel<<<dim3(1024), dim3(256), 0, stream>>>(v, out, P);
}